// Round 1
// baseline (614.977 us; speedup 1.0000x reference)
//
#include <hip/hip_runtime.h>
#include <math.h>

// Problem constants (fixed by the reference)
#define NSK   16       // skills
#define OBSD  376
#define ACTD  17
#define IND   393      // OBS + ACT
#define HD    256      // hidden width
#define MT    64       // rows (samples) per block tile
#define KC    32       // k-chunk for layer-1 x staging
#define XPAD  68       // padded row length for xs[k][r]: bank-friendly, 16B-aligned

// d_ws layout (as int):
//   [0..15]   counts per skill
//   [16..31]  exclusive offsets
//   [32..47]  scatter cursors
//   [48..48+B) permutation: skill-sorted sample indices

__device__ __forceinline__ float readlane_f(float v, int lane) {
    return __uint_as_float(__builtin_amdgcn_readlane(__float_as_uint(v), (unsigned)lane));
}

__global__ void hist_k(const int* __restrict__ sk, int* __restrict__ ws, int B) {
    __shared__ int h[NSK];
    if (threadIdx.x < NSK) h[threadIdx.x] = 0;
    __syncthreads();
    int i = blockIdx.x * blockDim.x + threadIdx.x;
    if (i < B) atomicAdd(&h[sk[i]], 1);
    __syncthreads();
    if (threadIdx.x < NSK) atomicAdd(&ws[threadIdx.x], h[threadIdx.x]);
}

__global__ void prefix_k(int* __restrict__ ws) {
    if (threadIdx.x == 0 && blockIdx.x == 0) {
        int acc = 0;
        for (int s = 0; s < NSK; ++s) {
            int c = ws[s];
            ws[16 + s] = acc;   // offsets
            ws[32 + s] = acc;   // cursors start at offsets
            acc += c;
        }
    }
}

__global__ void scatter_k(const int* __restrict__ sk, int* __restrict__ ws, int B) {
    int i = blockIdx.x * blockDim.x + threadIdx.x;
    if (i < B) {
        int s = sk[i];
        int pos = atomicAdd(&ws[32 + s], 1);
        ws[48 + pos] = i;
    }
}

// Fused 3-layer MLP over one 64-row, single-skill tile.
// 256 threads = 4 waves. Thread tile: 16 rows x 4 cols.
// rg = tid/64 (wave-uniform!) selects 16 rows; cg = tid%64 selects 4 cols.
// Wave-uniform rows let layer-2 fetch h1[r][k] via v_readlane (no LDS h).
__global__ __launch_bounds__(256) void moe_k(
    const float* __restrict__ obs, const float* __restrict__ act,
    const float* __restrict__ W1, const float* __restrict__ b1,
    const float* __restrict__ W2, const float* __restrict__ b2,
    const float* __restrict__ W3, const float* __restrict__ b3,
    const int* __restrict__ ws, float* __restrict__ out)
{
    __shared__ int rid[MT];
    __shared__ __align__(16) float xs[KC][XPAD];
    __shared__ int meta[3];

    const int tid = threadIdx.x;

    if (tid == 0) {
        // XCD-aware bijective swizzle: contiguous logical tile ids (skill-sorted)
        // land on the same XCD so each XCD's L2 holds ~2 skills' weights.
        int n = gridDim.x;
        int bid = blockIdx.x;
        int q = n >> 3, r = n & 7;
        int xcd = bid & 7, slot = bid >> 3;
        int lid = (xcd < r) ? (xcd * (q + 1) + slot)
                            : (r * (q + 1) + (xcd - r) * q + slot);
        int acc = 0, sid = -1, t = 0;
        for (int s = 0; s < NSK; ++s) {
            int c = ws[s];
            int tiles = (c + MT - 1) / MT;
            if (lid < acc + tiles) { sid = s; t = lid - acc; break; }
            acc += tiles;
        }
        meta[0] = sid;
        if (sid >= 0) {
            int cnt = ws[sid];
            meta[1] = ws[16 + sid] + t * MT;
            int nr = cnt - t * MT;
            meta[2] = nr < MT ? nr : MT;
        }
    }
    __syncthreads();
    const int sid = meta[0];
    if (sid < 0) return;
    const int start = meta[1];
    const int nrows = meta[2];

    const int* __restrict__ perm = ws + 48;
    if (tid < MT) {
        int i = tid < nrows ? tid : nrows - 1;   // clamp: dup rows, writes masked later
        rid[tid] = perm[start + i];
    }

    const int rg = tid >> 6;      // 0..3 (wave id) — wave-uniform
    const int cg = tid & 63;      // 0..63
    const int r0 = rg << 4;       // 16 rows
    const int c0 = cg << 2;       // 4 cols

    const float* __restrict__ W1s = W1 + sid * (IND * HD);
    const float* __restrict__ W2s = W2 + sid * (HD * HD);

    float acc1[16][4];
    #pragma unroll
    for (int i = 0; i < 16; ++i) {
        #pragma unroll
        for (int j = 0; j < 4; ++j) acc1[i][j] = 0.f;
    }

    // ---------------- layer 1: h1 = relu(x @ W1 + b1) ----------------
    const float* __restrict__ wp = W1s + c0;

#define L1_BODY(KIDX)                                                        \
    {                                                                        \
        const int k_ = (KIDX);                                               \
        float4 wv = *(const float4*)(wp + (k0 + k_) * HD);                   \
        const float4* xp = (const float4*)&xs[k_][r0];                       \
        float xr[16];                                                        \
        *(float4*)(xr + 0)  = xp[0];                                         \
        *(float4*)(xr + 4)  = xp[1];                                         \
        *(float4*)(xr + 8)  = xp[2];                                         \
        *(float4*)(xr + 12) = xp[3];                                         \
        _Pragma("unroll")                                                    \
        for (int i = 0; i < 16; ++i) {                                       \
            acc1[i][0] = fmaf(xr[i], wv.x, acc1[i][0]);                      \
            acc1[i][1] = fmaf(xr[i], wv.y, acc1[i][1]);                      \
            acc1[i][2] = fmaf(xr[i], wv.z, acc1[i][2]);                      \
            acc1[i][3] = fmaf(xr[i], wv.w, acc1[i][3]);                      \
        }                                                                    \
    }

    for (int c = 0; c < 13; ++c) {
        const int k0 = c * KC;
        __syncthreads();   // protect xs reuse (and rid on first pass)
        // stage x chunk transposed: xs[k][r]; lanes: consecutive k, same row
        #pragma unroll
        for (int it = 0; it < 8; ++it) {
            int lin = tid + (it << 8);      // 0..2047
            int k = lin & 31;
            int rr = lin >> 5;
            int g = k0 + k;
            int row = rid[rr];
            float v = 0.f;
            if (g < OBSD)      v = obs[row * OBSD + g];
            else if (g < IND)  v = act[row * ACTD + (g - OBSD)];
            xs[k][rr] = v;
        }
        __syncthreads();
        if (c < 12) {
            #pragma unroll 4
            for (int k = 0; k < KC; ++k) L1_BODY(k)
        } else {
            #pragma unroll
            for (int k = 0; k < (IND - 12 * KC); ++k) L1_BODY(k)
        }
    }
#undef L1_BODY

    // bias + relu -> h1 (in registers, distributed: lane cg holds cols c0..c0+3)
    float h1v[16][4];
    {
        float4 b1v = *(const float4*)(b1 + sid * HD + c0);
        #pragma unroll
        for (int i = 0; i < 16; ++i) {
            h1v[i][0] = fmaxf(acc1[i][0] + b1v.x, 0.f);
            h1v[i][1] = fmaxf(acc1[i][1] + b1v.y, 0.f);
            h1v[i][2] = fmaxf(acc1[i][2] + b1v.z, 0.f);
            h1v[i][3] = fmaxf(acc1[i][3] + b1v.w, 0.f);
        }
    }

    // ---------------- layer 2: h2 = relu(h1 @ W2 + b2) ----------------
    // h1[r][k] lives in lane (k>>2), reg (k&3) of this wave -> v_readlane.
    float acc2[16][4];
    #pragma unroll
    for (int i = 0; i < 16; ++i) {
        #pragma unroll
        for (int j = 0; j < 4; ++j) acc2[i][j] = 0.f;
    }
    {
        const float* __restrict__ w2p = W2s + c0;
        for (int kk = 0; kk < HD; kk += 4) {
            float4 wq[4];
            #pragma unroll
            for (int u = 0; u < 4; ++u) wq[u] = *(const float4*)(w2p + (kk + u) * HD);
            #pragma unroll
            for (int u = 0; u < 4; ++u) {
                const int src = (kk >> 2) + (u >> 2);   // uniform -> v_readlane
                const int reg = u & 3;
                #pragma unroll
                for (int i = 0; i < 16; ++i) {
                    float hv = readlane_f(h1v[i][reg], src);
                    acc2[i][0] = fmaf(hv, wq[u].x, acc2[i][0]);
                    acc2[i][1] = fmaf(hv, wq[u].y, acc2[i][1]);
                    acc2[i][2] = fmaf(hv, wq[u].z, acc2[i][2]);
                    acc2[i][3] = fmaf(hv, wq[u].w, acc2[i][3]);
                }
            }
        }
    }

    // ---------------- layer 3 + sigmoid + scatter-out ----------------
    {
        float4 b2v = *(const float4*)(b2 + sid * HD + c0);
        float4 w3v = *(const float4*)(W3 + sid * HD + c0);
        float part[16];
        #pragma unroll
        for (int i = 0; i < 16; ++i) {
            float h0 = fmaxf(acc2[i][0] + b2v.x, 0.f);
            float h1_ = fmaxf(acc2[i][1] + b2v.y, 0.f);
            float h2_ = fmaxf(acc2[i][2] + b2v.z, 0.f);
            float h3 = fmaxf(acc2[i][3] + b2v.w, 0.f);
            part[i] = h0 * w3v.x + h1_ * w3v.y + h2_ * w3v.z + h3 * w3v.w;
        }
        // full-wave (64-lane) butterfly reduction across the 64 col-groups
        #pragma unroll
        for (int i = 0; i < 16; ++i) {
            float p = part[i];
            #pragma unroll
            for (int off = 32; off > 0; off >>= 1)
                p += __shfl_xor(p, off, 64);
            part[i] = p;
        }
        if (cg == 0) {
            const float b3v = b3[sid];
            #pragma unroll
            for (int i = 0; i < 16; ++i) {
                int rr = r0 + i;
                if (rr < nrows) {
                    float logit = part[i] + b3v;
                    out[rid[rr]] = 1.f / (1.f + expf(-logit));
                }
            }
        }
    }
}

extern "C" void kernel_launch(void* const* d_in, const int* in_sizes, int n_in,
                              void* d_out, int out_size, void* d_ws, size_t ws_size,
                              hipStream_t stream)
{
    const float* obs = (const float*)d_in[0];
    const float* act = (const float*)d_in[1];
    const int*   sk  = (const int*)d_in[2];
    const float* W1  = (const float*)d_in[3];
    const float* b1  = (const float*)d_in[4];
    const float* W2  = (const float*)d_in[5];
    const float* b2  = (const float*)d_in[6];
    const float* W3  = (const float*)d_in[7];
    const float* b3  = (const float*)d_in[8];
    float* out = (float*)d_out;
    int B = in_sizes[2];
    int* ws = (int*)d_ws;

    // zero counts/offsets/cursors (ws is re-poisoned before every call)
    hipMemsetAsync(ws, 0, 48 * sizeof(int), stream);

    int nb = (B + 255) / 256;
    hipLaunchKernelGGL(hist_k,    dim3(nb), dim3(256), 0, stream, sk, ws, B);
    hipLaunchKernelGGL(prefix_k,  dim3(1),  dim3(64),  0, stream, ws);
    hipLaunchKernelGGL(scatter_k, dim3(nb), dim3(256), 0, stream, sk, ws, B);

    int ntiles = (B + MT - 1) / MT + NSK - 1;   // worst-case tile count (527)
    hipLaunchKernelGGL(moe_k, dim3(ntiles), dim3(256), 0, stream,
                       obs, act, W1, b1, W2, b2, W3, b3, ws, out);
}

// Round 3
// 291.958 us; speedup vs baseline: 2.1064x; 2.1064x over previous
//
#include <hip/hip_runtime.h>
#include <math.h>

// Problem constants (fixed by the reference)
#define NSK   16       // skills
#define OBSD  376
#define ACTD  17
#define IND   393      // OBS + ACT
#define HD    256      // hidden width
#define MT    32       // rows (samples) per block tile
#define KC    64       // k-chunk for layer-1 x staging
#define XPAD  36       // padded row len for xs[k][r]: %4==0 (16B-aligned), bank stride 4
#define NCH   7        // ceil(IND / KC)

// d_ws layout (ints):
//   [0..15]   counts per skill
//   [16..31]  exclusive offsets
//   [32..47]  scatter cursors
//   [48..64]  tile-prefix (17 entries)
//   [80..80+B) permutation: skill-sorted sample indices
#define WS_PERM 80

__device__ __forceinline__ float readlane_f(float v, int lane) {
    return __uint_as_float(__builtin_amdgcn_readlane(__float_as_uint(v), (unsigned)lane));
}

__global__ void hist_k(const int* __restrict__ sk, int* __restrict__ ws, int B) {
    __shared__ int h[NSK];
    if (threadIdx.x < NSK) h[threadIdx.x] = 0;
    __syncthreads();
    int i = blockIdx.x * blockDim.x + threadIdx.x;
    if (i < B) atomicAdd(&h[sk[i]], 1);
    __syncthreads();
    if (threadIdx.x < NSK) atomicAdd(&ws[threadIdx.x], h[threadIdx.x]);
}

__global__ void prefix_k(int* __restrict__ ws) {
    if (threadIdx.x == 0 && blockIdx.x == 0) {
        int acc = 0, tacc = 0;
        for (int s = 0; s < NSK; ++s) {
            int c = ws[s];
            ws[16 + s] = acc;    // row offsets
            ws[32 + s] = acc;    // scatter cursors
            ws[48 + s] = tacc;   // tile prefix
            acc  += c;
            tacc += (c + MT - 1) / MT;
        }
        ws[48 + NSK] = tacc;     // total tiles
    }
}

// Per-block aggregated scatter: 16 global atomics/block instead of 256.
__global__ void scatter_k(const int* __restrict__ sk, int* __restrict__ ws, int B) {
    __shared__ int lcnt[NSK];
    __shared__ int base[NSK];
    if (threadIdx.x < NSK) lcnt[threadIdx.x] = 0;
    __syncthreads();
    int i = blockIdx.x * blockDim.x + threadIdx.x;
    int s = 0, posl = 0;
    if (i < B) {
        s = sk[i];
        posl = atomicAdd(&lcnt[s], 1);
    }
    __syncthreads();
    if (threadIdx.x < NSK && lcnt[threadIdx.x] > 0)
        base[threadIdx.x] = atomicAdd(&ws[32 + threadIdx.x], lcnt[threadIdx.x]);
    __syncthreads();
    if (i < B) ws[WS_PERM + base[s] + posl] = i;
}

// Fused 3-layer MLP over one 32-row, single-skill tile.
// 256 threads = 4 waves. Thread tile: 8 rows x 4 cols.
// rg = tid>>6 (wave-uniform) selects 8 rows; cg = tid&63 selects 4 cols.
// Wave-uniform rows let layer-2 fetch h1[r][k] via v_readlane (no LDS h).
__global__ __launch_bounds__(256, 4) void moe_k(
    const float* __restrict__ obs, const float* __restrict__ act,
    const float* __restrict__ W1, const float* __restrict__ b1,
    const float* __restrict__ W2, const float* __restrict__ b2,
    const float* __restrict__ W3, const float* __restrict__ b3,
    const int* __restrict__ ws, float* __restrict__ out)
{
    __shared__ int rid[MT];
    __shared__ __align__(16) float xsA[KC][XPAD];
    __shared__ __align__(16) float xsB[KC][XPAD];
    __shared__ int meta[3];

    const int tid = threadIdx.x;

    // XCD-aware bijective swizzle (uniform across the block)
    int n = gridDim.x, bid = blockIdx.x;
    int q8 = n >> 3, r8 = n & 7;
    int xcd = bid & 7, slot = bid >> 3;
    int lid = (xcd < r8) ? (xcd * (q8 + 1) + slot)
                         : (r8 * (q8 + 1) + (xcd - r8) * q8 + slot);

    // parallel tile lookup: thread s checks skill s's tile range
    if (tid < NSK) {
        int t0 = ws[48 + tid], t1 = ws[48 + tid + 1];
        if (lid >= t0 && lid < t1) {
            int t   = lid - t0;
            int cnt = ws[tid];
            meta[0] = tid;
            meta[1] = ws[16 + tid] + t * MT;
            int nr  = cnt - t * MT;
            meta[2] = nr < MT ? nr : MT;
        }
    } else if (tid == 255) {
        if (lid >= ws[48 + NSK]) meta[0] = -1;   // exclusive with the tid<16 writer
    }
    __syncthreads();
    const int sid = meta[0];
    if (sid < 0) return;
    const int start = meta[1];
    const int nrows = meta[2];

    const int* __restrict__ perm = ws + WS_PERM;
    if (tid < MT) {
        int i = tid < nrows ? tid : nrows - 1;   // clamp: dup rows, writes masked later
        rid[tid] = perm[start + i];
    }
    __syncthreads();

    const int rg = tid >> 6;        // 0..3 (wave id) — wave-uniform
    const int cg = tid & 63;        // 0..63
    const int r0 = rg << 3;         // 8 rows per wave-group
    const int c0 = cg << 2;         // 4 cols
    const int rr_ = tid & 31;       // staging: my row slot
    const int qq  = tid >> 5;       // staging: my k sub-group (0..7)
    const long rowb = (long)rid[rr_];

    const float* __restrict__ W1s = W1 + (size_t)sid * (IND * HD);
    const float* __restrict__ W2s = W2 + (size_t)sid * (HD * HD);

    float acc1[8][4];
    #pragma unroll
    for (int i = 0; i < 8; ++i) {
        #pragma unroll
        for (int j = 0; j < 4; ++j) acc1[i][j] = 0.f;
    }

    // staging registers (T14 async split: load early, LDS-write late)
    float4 xq0, xq1;   // vector path (chunks 0..4, pure obs region)
    float  xr[8];      // scalar path (chunks 5..6, obs/act boundary + tail)

#define LOADC_VEC(C) {                                                       \
        const float* p = obs + rowb * OBSD + (C) * KC + 4 * qq;              \
        xq0 = *(const float4*)(p);                                           \
        xq1 = *(const float4*)(p + 32);                                      \
    }
#define LOADC_SCL(C) {                                                       \
        _Pragma("unroll")                                                    \
        for (int it = 0; it < 8; ++it) {                                     \
            int g = (C) * KC + it * 8 + qq;                                  \
            float v = 0.f;                                                   \
            if (g < OBSD)      v = obs[rowb * OBSD + g];                     \
            else if (g < IND)  v = act[rowb * ACTD + (g - OBSD)];            \
            xr[it] = v;                                                      \
        }                                                                    \
    }
#define WRITE_VEC(BUF) {                                                     \
        BUF[4*qq+0][rr_] = xq0.x; BUF[4*qq+1][rr_] = xq0.y;                  \
        BUF[4*qq+2][rr_] = xq0.z; BUF[4*qq+3][rr_] = xq0.w;                  \
        BUF[32+4*qq+0][rr_] = xq1.x; BUF[32+4*qq+1][rr_] = xq1.y;            \
        BUF[32+4*qq+2][rr_] = xq1.z; BUF[32+4*qq+3][rr_] = xq1.w;            \
    }
#define WRITE_SCL(BUF) {                                                     \
        _Pragma("unroll")                                                    \
        for (int it = 0; it < 8; ++it) BUF[it*8+qq][rr_] = xr[it];           \
    }
#define COMPUTE(BUF, C, KLIM) {                                              \
        const float* wpc = W1s + c0 + (size_t)(C) * KC * HD;                 \
        _Pragma("unroll 4")                                                  \
        for (int k = 0; k < (KLIM); ++k) {                                   \
            float4 wv = *(const float4*)(wpc + k * HD);                      \
            const float4* xp = (const float4*)&BUF[k][r0];                   \
            float xv[8];                                                     \
            *(float4*)(xv + 0) = xp[0];                                      \
            *(float4*)(xv + 4) = xp[1];                                      \
            _Pragma("unroll")                                                \
            for (int i = 0; i < 8; ++i) {                                    \
                acc1[i][0] = fmaf(xv[i], wv.x, acc1[i][0]);                  \
                acc1[i][1] = fmaf(xv[i], wv.y, acc1[i][1]);                  \
                acc1[i][2] = fmaf(xv[i], wv.z, acc1[i][2]);                  \
                acc1[i][3] = fmaf(xv[i], wv.w, acc1[i][3]);                  \
            }                                                                \
        }                                                                    \
    }

    // ---------------- layer 1: h1 = relu(x @ W1 + b1) ----------------
    // one barrier per chunk; 2 LDS buffers; next chunk's global loads issued
    // before the barrier so they fly during this chunk's compute.
    LOADC_VEC(0);
    #pragma unroll
    for (int c = 0; c < NCH; ++c) {
        float (*buf)[XPAD] = (c & 1) ? xsB : xsA;
        if (c < 5) { WRITE_VEC(buf); } else { WRITE_SCL(buf); }
        if (c + 1 < NCH) {
            if (c + 1 < 5) { LOADC_VEC(c + 1); } else { LOADC_SCL(c + 1); }
        }
        __syncthreads();
        if (c == 6) { COMPUTE(buf, c, IND - 6 * KC); }
        else        { COMPUTE(buf, c, KC); }
    }

    // bias + relu -> h1 (registers; lane cg holds cols c0..c0+3)
    float h1v[8][4];
    {
        float4 b1v = *(const float4*)(b1 + sid * HD + c0);
        #pragma unroll
        for (int i = 0; i < 8; ++i) {
            h1v[i][0] = fmaxf(acc1[i][0] + b1v.x, 0.f);
            h1v[i][1] = fmaxf(acc1[i][1] + b1v.y, 0.f);
            h1v[i][2] = fmaxf(acc1[i][2] + b1v.z, 0.f);
            h1v[i][3] = fmaxf(acc1[i][3] + b1v.w, 0.f);
        }
    }

    // ---------------- layer 2: h2 = relu(h1 @ W2 + b2) ----------------
    // h1[r][k] lives in lane (k>>2), reg (k&3) of this wave -> v_readlane.
    // Explicit A/B register prefetch: 8 k-rows of W2 in flight.
    float acc2[8][4];
    #pragma unroll
    for (int i = 0; i < 8; ++i) {
        #pragma unroll
        for (int j = 0; j < 4; ++j) acc2[i][j] = 0.f;
    }
    {
        const float* __restrict__ w2p = W2s + c0;
        float4 wqA[4], wqB[4];
        #pragma unroll
        for (int u = 0; u < 4; ++u) wqA[u] = *(const float4*)(w2p + u * HD);

#define L2_GRP(WQ, SRC) {                                                    \
        _Pragma("unroll")                                                    \
        for (int u = 0; u < 4; ++u) {                                        \
            _Pragma("unroll")                                                \
            for (int i = 0; i < 8; ++i) {                                    \
                float hv = readlane_f(h1v[i][u], (SRC));                     \
                acc2[i][0] = fmaf(hv, WQ[u].x, acc2[i][0]);                  \
                acc2[i][1] = fmaf(hv, WQ[u].y, acc2[i][1]);                  \
                acc2[i][2] = fmaf(hv, WQ[u].z, acc2[i][2]);                  \
                acc2[i][3] = fmaf(hv, WQ[u].w, acc2[i][3]);                  \
            }                                                                \
        }                                                                    \
    }

        for (int kk = 0; kk < HD; kk += 8) {
            #pragma unroll
            for (int u = 0; u < 4; ++u)
                wqB[u] = *(const float4*)(w2p + (kk + 4 + u) * HD);
            L2_GRP(wqA, kk >> 2);
            if (kk + 8 < HD) {
                #pragma unroll
                for (int u = 0; u < 4; ++u)
                    wqA[u] = *(const float4*)(w2p + (kk + 8 + u) * HD);
            }
            L2_GRP(wqB, (kk >> 2) + 1);
        }
#undef L2_GRP
    }

    // ---------------- layer 3 + sigmoid + scatter-out ----------------
    {
        float4 b2v = *(const float4*)(b2 + sid * HD + c0);
        float4 w3v = *(const float4*)(W3 + sid * HD + c0);
        float part[8];
        #pragma unroll
        for (int i = 0; i < 8; ++i) {
            float h0 = fmaxf(acc2[i][0] + b2v.x, 0.f);
            float h1_ = fmaxf(acc2[i][1] + b2v.y, 0.f);
            float h2_ = fmaxf(acc2[i][2] + b2v.z, 0.f);
            float h3 = fmaxf(acc2[i][3] + b2v.w, 0.f);
            part[i] = h0 * w3v.x + h1_ * w3v.y + h2_ * w3v.z + h3 * w3v.w;
        }
        #pragma unroll
        for (int i = 0; i < 8; ++i) {
            float p = part[i];
            #pragma unroll
            for (int off = 32; off > 0; off >>= 1)
                p += __shfl_xor(p, off, 64);
            part[i] = p;
        }
        if (cg == 0) {
            const float b3v = b3[sid];
            #pragma unroll
            for (int i = 0; i < 8; ++i) {
                int rr = r0 + i;
                if (rr < nrows) {
                    float logit = part[i] + b3v;
                    out[rid[rr]] = 1.f / (1.f + expf(-logit));
                }
            }
        }
    }
}

extern "C" void kernel_launch(void* const* d_in, const int* in_sizes, int n_in,
                              void* d_out, int out_size, void* d_ws, size_t ws_size,
                              hipStream_t stream)
{
    const float* obs = (const float*)d_in[0];
    const float* act = (const float*)d_in[1];
    const int*   sk  = (const int*)d_in[2];
    const float* W1  = (const float*)d_in[3];
    const float* b1  = (const float*)d_in[4];
    const float* W2  = (const float*)d_in[5];
    const float* b2  = (const float*)d_in[6];
    const float* W3  = (const float*)d_in[7];
    const float* b3  = (const float*)d_in[8];
    float* out = (float*)d_out;
    int B = in_sizes[2];
    int* ws = (int*)d_ws;

    // zero the histogram counters (offsets/cursors/tile-prefix are overwritten)
    hipMemsetAsync(ws, 0, 16 * sizeof(int), stream);

    int nb = (B + 255) / 256;
    hipLaunchKernelGGL(hist_k,    dim3(nb), dim3(256), 0, stream, sk, ws, B);
    hipLaunchKernelGGL(prefix_k,  dim3(1),  dim3(64),  0, stream, ws);
    hipLaunchKernelGGL(scatter_k, dim3(nb), dim3(256), 0, stream, sk, ws, B);

    int ntiles = (B + MT - 1) / MT + NSK - 1;   // worst-case tile count
    hipLaunchKernelGGL(moe_k, dim3(ntiles), dim3(256), 0, stream,
                       obs, act, W1, b1, W2, b2, W3, b3, ws, out);
}